// Round 1
// baseline (638.584 us; speedup 1.0000x reference)
//
#include <hip/hip_runtime.h>

#define NSUB 2500   // C(16,2)+C(16,3)+C(16,4)
#define NCOL 2516   // 16 + NSUB
#define NROW 16

struct SubTable { unsigned char idx[NSUB][4]; };

constexpr SubTable make_table() {
    SubTable tb{};
    int s = 0;
    for (int i = 0; i < NROW; ++i)
        for (int j = i + 1; j < NROW; ++j) {
            tb.idx[s][0] = (unsigned char)i; tb.idx[s][1] = (unsigned char)j;
            tb.idx[s][2] = 16;               tb.idx[s][3] = 16;  ++s;
        }
    for (int i = 0; i < NROW; ++i)
        for (int j = i + 1; j < NROW; ++j)
            for (int k = j + 1; k < NROW; ++k) {
                tb.idx[s][0] = (unsigned char)i; tb.idx[s][1] = (unsigned char)j;
                tb.idx[s][2] = (unsigned char)k; tb.idx[s][3] = 16;  ++s;
            }
    for (int i = 0; i < NROW; ++i)
        for (int j = i + 1; j < NROW; ++j)
            for (int k = j + 1; k < NROW; ++k)
                for (int l = k + 1; l < NROW; ++l) {
                    tb.idx[s][0] = (unsigned char)i; tb.idx[s][1] = (unsigned char)j;
                    tb.idx[s][2] = (unsigned char)k; tb.idx[s][3] = (unsigned char)l;  ++s;
                }
    return tb;
}

__constant__ SubTable g_tab = make_table();

// One block per row. 16 threads compute t_j = (1/x_j - 1)^lam into LDS
// (slot 16 = 0.0 pad so every subset is a uniform 4-term sum), then all
// 256 threads stride the 2500 subsets with coalesced output writes.
__global__ __launch_bounds__(256) void dombi_kernel(const float* __restrict__ x,
                                                    const float* __restrict__ lam_p,
                                                    float* __restrict__ out) {
    __shared__ float t[17];
    const int   row     = blockIdx.x;
    const int   tid     = threadIdx.x;
    const float lam     = lam_p[0];
    const float inv_lam = 1.0f / lam;

    const float* xr   = x   + (size_t)row * NROW;
    float*       orow = out + (size_t)row * NCOL;

    if (tid < NROW) {
        float xv = xr[tid];
        orow[tid] = xv;                         // pass-through columns 0..15
        t[tid] = powf(1.0f / xv - 1.0f, lam);
    } else if (tid == NROW) {
        t[NROW] = 0.0f;                         // zero pad slot
    }
    __syncthreads();

    const uchar4* cp = reinterpret_cast<const uchar4*>(&g_tab.idx[0][0]);
    for (int s = tid; s < NSUB; s += 256) {
        uchar4 c = cp[s];
        float sum = t[c.x] + t[c.y] + t[c.z] + t[c.w];
        orow[NROW + s] = 1.0f / (1.0f + powf(sum, inv_lam));
    }
}

extern "C" void kernel_launch(void* const* d_in, const int* in_sizes, int n_in,
                              void* d_out, int out_size, void* d_ws, size_t ws_size,
                              hipStream_t stream) {
    const float* x   = (const float*)d_in[0];
    const float* lam = (const float*)d_in[1];
    float*       out = (float*)d_out;
    const int B = in_sizes[0] / NROW;   // 32768
    dombi_kernel<<<B, 256, 0, stream>>>(x, lam, out);
}

// Round 2
// 358.122 us; speedup vs baseline: 1.7831x; 1.7831x over previous
//
#include <hip/hip_runtime.h>

#define NSUB 2500   // C(16,2)+C(16,3)+C(16,4)
#define NCOL 2516   // 16 + NSUB
#define NROW 16
#define NQUAD 625   // NSUB / 4

struct SubTable { unsigned char idx[NSUB][4]; };

constexpr SubTable make_table() {
    SubTable tb{};
    int s = 0;
    for (int i = 0; i < NROW; ++i)
        for (int j = i + 1; j < NROW; ++j) {
            tb.idx[s][0] = (unsigned char)i; tb.idx[s][1] = (unsigned char)j;
            tb.idx[s][2] = 16;               tb.idx[s][3] = 16;  ++s;
        }
    for (int i = 0; i < NROW; ++i)
        for (int j = i + 1; j < NROW; ++j)
            for (int k = j + 1; k < NROW; ++k) {
                tb.idx[s][0] = (unsigned char)i; tb.idx[s][1] = (unsigned char)j;
                tb.idx[s][2] = (unsigned char)k; tb.idx[s][3] = 16;  ++s;
            }
    for (int i = 0; i < NROW; ++i)
        for (int j = i + 1; j < NROW; ++j)
            for (int k = j + 1; k < NROW; ++k)
                for (int l = k + 1; l < NROW; ++l) {
                    tb.idx[s][0] = (unsigned char)i; tb.idx[s][1] = (unsigned char)j;
                    tb.idx[s][2] = (unsigned char)k; tb.idx[s][3] = (unsigned char)l;  ++s;
                }
    return tb;
}

__constant__ SubTable g_tab = make_table();

typedef float f32x4 __attribute__((ext_vector_type(4)));

// h = 1/(1 + sum^(1/lam)) via raw HW transcendentals:
//   v_log_f32 (log2) + v_mul + v_exp_f32 (2^x) + v_add + v_rcp_f32
// sum in [~0.8, ~10] so no edge cases; ~1 ulp per transcendental,
// amplified error in h ~1e-6 << the 2e-3 absmax we pass with.
__device__ __forceinline__ float hval(float s, float p) {
    float q = __builtin_amdgcn_logf(s);        // log2(s)
    float e = __builtin_amdgcn_exp2f(p * q);   // s^p
    return __builtin_amdgcn_rcpf(1.0f + e);
}

// One block per row. 16 threads compute t_j = (1/x_j - 1)^lam into LDS
// (slot 16 = 0.0 pad so every subset is a uniform 4-term sum), then all
// 256 threads process 4 subsets each per iteration with float4
// nontemporal stores (streaming output, no reuse).
__global__ __launch_bounds__(256) void dombi_kernel(const float* __restrict__ x,
                                                    const float* __restrict__ lam_p,
                                                    float* __restrict__ out) {
    __shared__ float t[17];
    const int   row     = blockIdx.x;
    const int   tid     = threadIdx.x;
    const float lam     = lam_p[0];
    const float inv_lam = 1.0f / lam;

    const float* xr   = x   + (size_t)row * NROW;
    float*       orow = out + (size_t)row * NCOL;

    if (tid < NROW) {
        float xv = xr[tid];
        t[tid] = powf(1.0f / xv - 1.0f, lam);   // accurate: only 16/row
    } else if (tid == NROW) {
        t[NROW] = 0.0f;                         // zero pad slot
    }
    if (tid < 4) {                              // pass-through cols 0..15, vectorized
        reinterpret_cast<f32x4*>(orow)[tid] =
            reinterpret_cast<const f32x4*>(xr)[tid];
    }
    __syncthreads();

    const uchar4* cp = reinterpret_cast<const uchar4*>(&g_tab.idx[0][0]);
    f32x4*        o4 = reinterpret_cast<f32x4*>(orow + NROW);   // 16B-aligned

    for (int s4 = tid; s4 < NQUAD; s4 += 256) {
        const int s = s4 * 4;
        uchar4 c0 = cp[s + 0];
        uchar4 c1 = cp[s + 1];
        uchar4 c2 = cp[s + 2];
        uchar4 c3 = cp[s + 3];
        f32x4 r;
        r.x = hval(t[c0.x] + t[c0.y] + t[c0.z] + t[c0.w], inv_lam);
        r.y = hval(t[c1.x] + t[c1.y] + t[c1.z] + t[c1.w], inv_lam);
        r.z = hval(t[c2.x] + t[c2.y] + t[c2.z] + t[c2.w], inv_lam);
        r.w = hval(t[c3.x] + t[c3.y] + t[c3.z] + t[c3.w], inv_lam);
        __builtin_nontemporal_store(r, &o4[s4]);
    }
}

extern "C" void kernel_launch(void* const* d_in, const int* in_sizes, int n_in,
                              void* d_out, int out_size, void* d_ws, size_t ws_size,
                              hipStream_t stream) {
    const float* x   = (const float*)d_in[0];
    const float* lam = (const float*)d_in[1];
    float*       out = (float*)d_out;
    const int B = in_sizes[0] / NROW;   // 32768
    dombi_kernel<<<B, 256, 0, stream>>>(x, lam, out);
}